// Round 5
// baseline (398.113 us; speedup 1.0000x reference)
//
#include <hip/hip_runtime.h>
#include <hip/hip_bf16.h>

typedef unsigned int uint;
typedef unsigned short ushort;

#define N_NODES 60000
#define N_EDGES 600000
#define NREL 7
#define NSEG (N_NODES * 8)    // (node, rel) segments, node-major, rel padded to 8
#define D_IN 64
#define DHID 128
#define LEPS 1e-5f

typedef __attribute__((ext_vector_type(8))) short bf16x8v;   // 8 bf16 = 4 VGPRs
typedef __attribute__((ext_vector_type(4))) float f32x4v;    // MFMA accumulator

#define AS1C(p) ((const __attribute__((address_space(1))) void*)(p))
#define AS3(p)  ((__attribute__((address_space(3))) void*)(p))

__device__ __forceinline__ float bf2f(uint u16) {
    return __uint_as_float(u16 << 16);
}
__device__ __forceinline__ uint f2bf(float f) {
    uint u = __float_as_uint(f);
    uint lsb = (u >> 16) & 1u;
    u += 0x7fffu + lsb;
    return u >> 16;
}
__device__ __forceinline__ uint pack2(float a, float b) {
    return f2bf(a) | (f2bf(b) << 16);
}

// ---------------- embedding: h0 = clip(x,-10,10) @ emb_W + emb_b (bf16 out) ----
__global__ __launch_bounds__(256) void k_embed(const float* __restrict__ x,
                                               const float* __restrict__ W,
                                               const float* __restrict__ bias,
                                               ushort* __restrict__ h) {
    __shared__ float Ws[D_IN * DHID];   // 32 KB
    __shared__ float xs[2][D_IN];
    __shared__ float brow[DHID];
    for (int i = threadIdx.x; i < D_IN * DHID; i += 256) Ws[i] = W[i];
    for (int i = threadIdx.x; i < DHID; i += 256) brow[i] = bias[i];
    const int g = threadIdx.x >> 7;      // node slot 0/1 in block
    const int c = threadIdx.x & 127;     // output column
    const int nb = gridDim.x;
    const int iters = (N_NODES + nb * 2 - 1) / (nb * 2);
    for (int it = 0; it < iters; ++it) {
        const int n = (it * nb + blockIdx.x) * 2 + g;
        __syncthreads();
        if (n < N_NODES && c < D_IN) {
            float v = x[(size_t)n * D_IN + c];
            xs[g][c] = fminf(fmaxf(v, -10.f), 10.f);
        }
        __syncthreads();
        if (n < N_NODES) {
            float acc = brow[c];
            #pragma unroll
            for (int k = 0; k < D_IN; ++k) acc = fmaf(xs[g][k], Ws[k * DHID + c], acc);
            h[(size_t)n * DHID + c] = (ushort)f2bf(acc);
        }
    }
}

// ---------------- B transpose + f32->bf16: Bt[l][j 0..127][k 0..1023] ----------
__global__ __launch_bounds__(256) void k_bt(const float* __restrict__ relW,
                                            const float* __restrict__ rootW,
                                            ushort* __restrict__ Bt) {
    const int l  = blockIdx.x >> 5;
    const int kt = (blockIdx.x >> 1) & 15;   // 64-k tile
    const int jt = blockIdx.x & 1;           // 64-j tile
    __shared__ float t[64][65];
    const int tid = threadIdx.x;
    #pragma unroll
    for (int i = 0; i < 4; ++i) {
        const int idx = i * 256 + tid;       // 0..1023
        const int kr = idx >> 4;             // 0..63
        const int j4 = idx & 15;             // float4 index
        const int kg = kt * 64 + kr;
        const float* src = (kg < 896)
            ? (relW + (size_t)l * 896 * 128 + (size_t)kg * 128)
            : (rootW + (size_t)l * 128 * 128 + (size_t)(kg - 896) * 128);
        const float4 v = *(const float4*)(src + jt * 64 + j4 * 4);
        t[kr][j4 * 4 + 0] = v.x; t[kr][j4 * 4 + 1] = v.y;
        t[kr][j4 * 4 + 2] = v.z; t[kr][j4 * 4 + 3] = v.w;
    }
    __syncthreads();
    uint* btd = (uint*)Bt;
    #pragma unroll
    for (int i = 0; i < 8; ++i) {
        const int idx = i * 256 + tid;       // 0..2047
        const int jr = idx >> 5;             // 0..63
        const int kd = idx & 31;             // dword within 64-k tile
        const uint w = pack2(t[kd * 2][jr], t[kd * 2 + 1][jr]);
        btd[(size_t)l * 65536 + (size_t)(jt * 64 + jr) * 512 + kt * 32 + kd] = w;
    }
}

// ---------------- CSR build over (dst, rel) segments, node-major --------------
__global__ void k_zero(int* __restrict__ a, int n) {
    const int i = blockIdx.x * 256 + threadIdx.x;
    if (i < n) a[i] = 0;
}
__global__ void k_deg(const int* __restrict__ dst, const int* __restrict__ et,
                      int* __restrict__ deg) {
    for (int e = blockIdx.x * 256 + threadIdx.x; e < N_EDGES; e += gridDim.x * 256)
        atomicAdd(&deg[dst[e] * 8 + et[e]], 1);
}
__global__ void k_scan1(const int* __restrict__ in, int* __restrict__ out,
                        int* __restrict__ bsum, int n) {
    __shared__ int s[256];
    const int t = threadIdx.x;
    const int i = blockIdx.x * 256 + t;
    const int v = (i < n) ? in[i] : 0;
    s[t] = v;
    __syncthreads();
    for (int o = 1; o < 256; o <<= 1) {
        int uu = (t >= o) ? s[t - o] : 0;
        __syncthreads();
        s[t] += uu;
        __syncthreads();
    }
    if (i < n) out[i] = s[t] - v;   // exclusive within block
    if (t == 255) bsum[blockIdx.x] = s[255];
}
// single-block looped scan over nb block sums (carry across 256-chunks)
__global__ void k_scanmid(int* __restrict__ bs, int nb) {
    __shared__ int s[256];
    __shared__ int carrys;
    const int t = threadIdx.x;
    if (t == 0) carrys = 0;
    __syncthreads();
    const int nch = (nb + 255) / 256;
    for (int ch = 0; ch < nch; ++ch) {
        const int i = ch * 256 + t;
        const int v = (i < nb) ? bs[i] : 0;
        s[t] = v;
        __syncthreads();
        for (int o = 1; o < 256; o <<= 1) {
            int uu = (t >= o) ? s[t - o] : 0;
            __syncthreads();
            s[t] += uu;
            __syncthreads();
        }
        const int carry = carrys;
        if (i < nb) bs[i] = s[t] - v + carry;
        __syncthreads();
        if (t == 255) carrys = carry + s[255];
        __syncthreads();
    }
}
__global__ void k_scanadd(int* __restrict__ a, const int* __restrict__ bsums,
                          int n, int setlast) {
    const int i = blockIdx.x * 256 + threadIdx.x;
    if (i < n) a[i] += bsums[blockIdx.x];
    if (setlast && blockIdx.x == 0 && threadIdx.x == 0) a[n] = N_EDGES;
}
__global__ void k_scatter(const int* __restrict__ src, const int* __restrict__ dst,
                          const int* __restrict__ et, const int* __restrict__ rp,
                          int* __restrict__ fill, ushort* __restrict__ csr16) {
    for (int e = blockIdx.x * 256 + threadIdx.x; e < N_EDGES; e += gridDim.x * 256) {
        const int key = dst[e] * 8 + et[e];
        const int p = rp[key] + atomicAdd(&fill[key], 1);
        csr16[p] = (ushort)src[e];    // src < 65536
    }
}

// ---------------- phase-split fused: gather-all -> MFMA GEMM -> LN+ReLU -------
// Phase 1: 256 threads = 64 nodes x 4 col-chunks(32) gather ALL 7 relation
//   means into a 64x896 bf16 LDS A-tile (XOR-swizzled 16B granules). One 32B
//   rp load per node gives all segment bounds; rel loop fully unrolled; 4-wide
//   edge batches -> max MLP, zero barriers.
// Phase 2: 16 k-tiles: A from LDS (kt<14) or global h (root, kt 14/15); B
//   double-buffered global_load_lds w/ pre-swizzled source, counted vmcnt(4)
//   (B is now the ONLY load type in the vmcnt domain -> exact counting).
__global__ __launch_bounds__(256, 1) void k_fused(const uint* __restrict__ h32,  // [N][64] dwords
                                                  const int* __restrict__ rp,    // [NSEG+1]
                                                  const ushort* __restrict__ csr16,
                                                  const ushort* __restrict__ Bt, // [128][1024]
                                                  const float* __restrict__ bias,
                                                  const float* __restrict__ g,
                                                  const float* __restrict__ bb,
                                                  uint* __restrict__ out,        // bf16 dwords
                                                  int nrows) {
    __shared__ alignas(16) union {
        struct { ushort a[64 * 896]; ushort b[2][128 * 64]; } s;  // 112 + 32 KB
        float ep[64 * 132];                                       // 33 KB epilogue
    } u;
    __shared__ float sbi[DHID], sg[DHID], sbb[DHID];

    const int tid = threadIdx.x;
    if (tid < DHID) { sbi[tid] = bias[tid]; sg[tid] = g[tid]; sbb[tid] = bb[tid]; }
    const int lane = tid & 63;
    const int wid = tid >> 6;          // 0..3
    const int wrow = wid >> 1;         // 0..1: 32-row band
    const int wcol = wid & 1;          // 0..1: 64-col band
    const int l15 = lane & 15, lh = lane >> 4;
    const int row0 = blockIdx.x * 64;

    // ---- B staging: linear LDS dest (wave-uniform base), swizzled source ----
    auto stageB = [&](int buf, int kt) {
        #pragma unroll
        for (int q = 0; q < 4; ++q) {
            const int p = q * 256 + tid;                 // granule 0..1023
            const int row = p >> 3;
            const int G = (p & 7) ^ (row & 7);
            const ushort* gb = Bt + (size_t)row * 1024 + kt * 64 + G * 8;
            __builtin_amdgcn_global_load_lds(AS1C(gb),
                AS3(&u.s.b[buf][(q * 256 + wid * 64) * 8]), 16, 0, 0);
        }
    };
    stageB(0, 0);   // in flight under all of phase 1

    // ================= phase 1: gather-all =================
    {
        const int nl = tid >> 2;           // node-local 0..63
        const int cc = tid & 3;            // 32-col chunk
        const int n  = min(row0 + nl, nrows - 1);
        const int4 rpa = *(const int4*)(rp + n * 8);
        const int4 rpb = *(const int4*)(rp + n * 8 + 4);
        const int bnd[8] = {rpa.x, rpa.y, rpa.z, rpa.w, rpb.x, rpb.y, rpb.z, rpb.w};

        float ac[32];
        auto accum = [&](int s) {
            const uint* hp = h32 + (size_t)s * 64 + cc * 16;
            const uint4 q0 = *(const uint4*)(hp + 0);
            const uint4 q1 = *(const uint4*)(hp + 4);
            const uint4 q2 = *(const uint4*)(hp + 8);
            const uint4 q3 = *(const uint4*)(hp + 12);
            const uint d[16] = {q0.x, q0.y, q0.z, q0.w, q1.x, q1.y, q1.z, q1.w,
                                q2.x, q2.y, q2.z, q2.w, q3.x, q3.y, q3.z, q3.w};
            #pragma unroll
            for (int i = 0; i < 16; ++i) {
                ac[2 * i]     += bf2f(d[i] & 0xFFFFu);
                ac[2 * i + 1] += bf2f(d[i] >> 16);
            }
        };
        ushort* arow = &u.s.a[nl * 896];
        #pragma unroll
        for (int r = 0; r < NREL; ++r) {
            const int beg = bnd[r], end = bnd[r + 1];
            #pragma unroll
            for (int i = 0; i < 32; ++i) ac[i] = 0.f;
            #pragma unroll 1
            for (int e = beg; e < end; e += 4) {
                const int rem = end - e;
                const int i0 = (int)csr16[e];
                const int i1 = rem > 1 ? (int)csr16[e + 1] : -1;
                const int i2 = rem > 2 ? (int)csr16[e + 2] : -1;
                const int i3 = rem > 3 ? (int)csr16[e + 3] : -1;
                accum(i0);
                if (i1 >= 0) accum(i1);
                if (i2 >= 0) accum(i2);
                if (i3 >= 0) accum(i3);
            }
            const float sc = 1.f / (float)max(end - beg, 1);
            uint w[16];
            #pragma unroll
            for (int i = 0; i < 16; ++i) w[i] = pack2(ac[2 * i] * sc, ac[2 * i + 1] * sc);
            const int gb0 = r * 16 + cc * 4;
            #pragma unroll
            for (int i = 0; i < 4; ++i) {
                const int slot = (gb0 + i) ^ (nl & 7);
                *(uint4*)&arow[slot * 8] = make_uint4(w[4 * i], w[4 * i + 1],
                                                      w[4 * i + 2], w[4 * i + 3]);
            }
        }
    }
    __syncthreads();   // full drain: gathers + stageB(0,0) complete, A-tile visible

    // ================= phase 2: pipelined MFMA GEMM =================
    f32x4v acc[2][4];
    #pragma unroll
    for (int fm = 0; fm < 2; ++fm)
        #pragma unroll
        for (int fn = 0; fn < 4; ++fn)
            acc[fm][fn] = (f32x4v){0.f, 0.f, 0.f, 0.f};

    #pragma unroll 1
    for (int kt = 0; kt < 16; ++kt) {
        const int cur = kt & 1;
        if (kt < 15) {
            stageB(cur ^ 1, kt + 1);       // 4 loads in flight across barrier
            asm volatile("s_waitcnt vmcnt(4)\n\ts_barrier" ::: "memory");
        } else {
            asm volatile("s_waitcnt vmcnt(0)\n\ts_barrier" ::: "memory");
        }
        #pragma unroll
        for (int kh = 0; kh < 2; ++kh) {
            bf16x8v af[2], bfr[4];
            if (kt < 14) {
                #pragma unroll
                for (int fm = 0; fm < 2; ++fm) {
                    const int rowa = wrow * 32 + fm * 16 + l15;
                    const int slot = (kt * 8 + kh * 4 + lh) ^ (rowa & 7);
                    af[fm] = *(const bf16x8v*)&u.s.a[rowa * 896 + slot * 8];
                }
            } else {
                #pragma unroll
                for (int fm = 0; fm < 2; ++fm) {
                    const int rg = min(row0 + wrow * 32 + fm * 16 + l15, nrows - 1);
                    af[fm] = *(const bf16x8v*)(h32 + (size_t)rg * 64 +
                                               (kt - 14) * 32 + kh * 16 + lh * 4);
                }
            }
            #pragma unroll
            for (int fn = 0; fn < 4; ++fn) {
                const int rowb = wcol * 64 + fn * 16 + l15;
                const int slot = (kh * 4 + lh) ^ (rowb & 7);
                bfr[fn] = *(const bf16x8v*)&u.s.b[cur][rowb * 64 + slot * 8];
            }
            #pragma unroll
            for (int fm = 0; fm < 2; ++fm)
                #pragma unroll
                for (int fn = 0; fn < 4; ++fn)
                    acc[fm][fn] = __builtin_amdgcn_mfma_f32_16x16x32_bf16(
                        af[fm], bfr[fn], acc[fm][fn], 0, 0, 0);
        }
        asm volatile("s_barrier" ::: "memory");   // protect cur before overwrite
    }
    __syncthreads();

    // ================= fused LayerNorm + ReLU epilogue =================
    #pragma unroll
    for (int fm = 0; fm < 2; ++fm) {
        const int rl = wrow * 32 + fm * 16 + lh * 4;
        #pragma unroll
        for (int fn = 0; fn < 4; ++fn) {
            const int cl = wcol * 64 + fn * 16 + l15;
            const float bi = sbi[cl];
            #pragma unroll
            for (int r = 0; r < 4; ++r)
                u.ep[(rl + r) * 132 + cl] = acc[fm][fn][r] + bi;
        }
    }
    __syncthreads();
    {
        const int r_loc = tid >> 2, cb = tid & 3;   // 4 threads per row
        const int row_g = row0 + r_loc;
        float v[32];
        float s = 0.f, sq = 0.f;
        #pragma unroll
        for (int q = 0; q < 8; ++q) {
            const float4 t4 = *(const float4*)&u.ep[r_loc * 132 + cb * 32 + q * 4];
            v[4 * q + 0] = t4.x; v[4 * q + 1] = t4.y;
            v[4 * q + 2] = t4.z; v[4 * q + 3] = t4.w;
            s += t4.x + t4.y + t4.z + t4.w;
            sq += t4.x * t4.x + t4.y * t4.y + t4.z * t4.z + t4.w * t4.w;
        }
        s += __shfl_xor(s, 1, 64); sq += __shfl_xor(sq, 1, 64);
        s += __shfl_xor(s, 2, 64); sq += __shfl_xor(sq, 2, 64);
        const float mean = s * (1.f / 128.f);
        const float var = sq * (1.f / 128.f) - mean * mean;
        const float rs = rsqrtf(var + LEPS);
        if (row_g < nrows) {
            uint o[16];
            #pragma unroll
            for (int q2 = 0; q2 < 16; ++q2) {
                const int c0 = cb * 32 + 2 * q2;
                const float va = fmaxf((v[2 * q2]     - mean) * rs * sg[c0]     + sbb[c0],     0.f);
                const float vb = fmaxf((v[2 * q2 + 1] - mean) * rs * sg[c0 + 1] + sbb[c0 + 1], 0.f);
                o[q2] = pack2(va, vb);
            }
            uint* op = out + (size_t)row_g * 64 + cb * 16;
            *(uint4*)(op + 0)  = make_uint4(o[0], o[1], o[2], o[3]);
            *(uint4*)(op + 4)  = make_uint4(o[4], o[5], o[6], o[7]);
            *(uint4*)(op + 8)  = make_uint4(o[8], o[9], o[10], o[11]);
            *(uint4*)(op + 12) = make_uint4(o[12], o[13], o[14], o[15]);
        }
    }
}

// ---------------- classifier: MFMA h@W1 + in-register LN/ReLU/W2-dot ----------
__global__ __launch_bounds__(256) void k_cls(const ushort* __restrict__ h16,
                                             const float* __restrict__ W1,   // [128][64]
                                             const float* __restrict__ b1,
                                             const float* __restrict__ lg,
                                             const float* __restrict__ lb,
                                             const float* __restrict__ W2,   // [64]
                                             const float* __restrict__ b2,
                                             float* __restrict__ outp, int nrows) {
    __shared__ ushort Bs[16 * 64 * 8];   // [k-granule g][col j'][8 bf16], 16 KB
    const int tid = threadIdx.x;
    #pragma unroll
    for (int i = 0; i < 8; ++i) {
        const int q = i * 256 + tid;     // 2048 float4 = 8192 f32
        const int k = q >> 4;            // 0..127
        const int j0 = (q & 15) * 4;
        const float4 w = *(const float4*)(W1 + (size_t)k * 64 + j0);
        const int gg = k >> 3, kp = k & 7;
        const int jx = (gg & 3) << 4;
        Bs[(gg * 64 + ((j0 + 0) ^ jx)) * 8 + kp] = (ushort)f2bf(w.x);
        Bs[(gg * 64 + ((j0 + 1) ^ jx)) * 8 + kp] = (ushort)f2bf(w.y);
        Bs[(gg * 64 + ((j0 + 2) ^ jx)) * 8 + kp] = (ushort)f2bf(w.z);
        Bs[(gg * 64 + ((j0 + 3) ^ jx)) * 8 + kp] = (ushort)f2bf(w.w);
    }
    const int lane = tid & 63, wid = tid >> 6;
    const int l15 = lane & 15, lh = lane >> 4;
    float lgv[4], lbv[4], w2v[4], b1v[4];
    #pragma unroll
    for (int fn = 0; fn < 4; ++fn) {
        const int col = fn * 16 + l15;
        lgv[fn] = lg[col]; lbv[fn] = lb[col]; w2v[fn] = W2[col]; b1v[fn] = b1[col];
    }
    const float b2v = b2[0];
    __syncthreads();

    const int row0 = blockIdx.x * 128;
    f32x4v acc[2][4];
    #pragma unroll
    for (int fm = 0; fm < 2; ++fm)
        #pragma unroll
        for (int fn = 0; fn < 4; ++fn)
            acc[fm][fn] = (f32x4v){0.f, 0.f, 0.f, 0.f};

    #pragma unroll
    for (int kk = 0; kk < 4; ++kk) {
        bf16x8v af[2], bfr[4];
        #pragma unroll
        for (int fm = 0; fm < 2; ++fm) {
            const int row = min(row0 + wid * 32 + fm * 16 + l15, nrows - 1);
            af[fm] = *(const bf16x8v*)(h16 + (size_t)row * 128 + kk * 32 + lh * 8);
        }
        #pragma unroll
        for (int fn = 0; fn < 4; ++fn) {
            const int gg = kk * 4 + lh;
            const int jc = fn * 16 + l15;
            bfr[fn] = *(const bf16x8v*)&Bs[(gg * 64 + (jc ^ ((gg & 3) << 4))) * 8];
        }
        #pragma unroll
        for (int fm = 0; fm < 2; ++fm)
            #pragma unroll
            for (int fn = 0; fn < 4; ++fn)
                acc[fm][fn] = __builtin_amdgcn_mfma_f32_16x16x32_bf16(
                    af[fm], bfr[fn], acc[fm][fn], 0, 0, 0);
    }

    #pragma unroll
    for (int fm = 0; fm < 2; ++fm)
        #pragma unroll
        for (int r = 0; r < 4; ++r) {
            float cv[4];
            float s = 0.f, sq = 0.f;
            #pragma unroll
            for (int fn = 0; fn < 4; ++fn) {
                cv[fn] = acc[fm][fn][r] + b1v[fn];
                s += cv[fn]; sq += cv[fn] * cv[fn];
            }
            s += __shfl_xor(s, 1, 64); sq += __shfl_xor(sq, 1, 64);
            s += __shfl_xor(s, 2, 64); sq += __shfl_xor(sq, 2, 64);
            s += __shfl_xor(s, 4, 64); sq += __shfl_xor(sq, 4, 64);
            s += __shfl_xor(s, 8, 64); sq += __shfl_xor(sq, 8, 64);
            const float mean = s * (1.f / 64.f);
            const float var = sq * (1.f / 64.f) - mean * mean;
            const float rs = rsqrtf(var + LEPS);
            float dot = 0.f;
            #pragma unroll
            for (int fn = 0; fn < 4; ++fn)
                dot += fmaxf((cv[fn] - mean) * rs * lgv[fn] + lbv[fn], 0.f) * w2v[fn];
            dot += __shfl_xor(dot, 1, 64);
            dot += __shfl_xor(dot, 2, 64);
            dot += __shfl_xor(dot, 4, 64);
            dot += __shfl_xor(dot, 8, 64);
            const int row = row0 + wid * 32 + fm * 16 + lh * 4 + r;
            if (l15 == 0 && row < nrows) outp[row] = dot + b2v;
        }
}

extern "C" void kernel_launch(void* const* d_in, const int* in_sizes, int n_in,
                              void* d_out, int out_size, void* d_ws, size_t ws_size,
                              hipStream_t stream) {
    const float* x      = (const float*)d_in[0];
    const int*   eidx   = (const int*)d_in[1];
    const int*   etype  = (const int*)d_in[2];
    const float* emb_W  = (const float*)d_in[3];
    const float* emb_b  = (const float*)d_in[4];
    const float* rel_W  = (const float*)d_in[5];
    const float* root_W = (const float*)d_in[6];
    const float* conv_b = (const float*)d_in[7];
    const float* ln_g   = (const float*)d_in[8];
    const float* ln_b   = (const float*)d_in[9];
    const float* cls_W1 = (const float*)d_in[10];
    const float* cls_b1 = (const float*)d_in[11];
    const float* cls_lg = (const float*)d_in[12];
    const float* cls_lb = (const float*)d_in[13];
    const float* cls_W2 = (const float*)d_in[14];
    const float* cls_b2 = (const float*)d_in[15];

    const int* srcv = eidx;
    const int* dstv = eidx + N_EDGES;

    // workspace layout (~40 MB)
    char* ws = (char*)d_ws;
    size_t off = 0;
    auto alloc = [&](size_t bytes) { void* p = ws + off; off += (bytes + 255) & ~(size_t)255; return p; };
    uint*   h0    = (uint*)alloc((size_t)N_NODES * 64 * 4);     // bf16 h, dword-packed
    uint*   h1    = (uint*)alloc((size_t)N_NODES * 64 * 4);
    int*    rp    = (int*)alloc((size_t)(NSEG + 1) * 4);
    int*    deg   = (int*)alloc((size_t)2 * NSEG * 4);          // deg | fill
    ushort* csr16 = (ushort*)alloc((size_t)N_EDGES * 2);
    ushort* Btb   = (ushort*)alloc((size_t)2 * 128 * 1024 * 2); // bf16 B^T per layer
    int*    bs    = (int*)alloc(8192 * 4);
    int*    fill  = deg + NSEG;
    (void)ws_size; (void)n_in; (void)in_sizes; (void)out_size;

    const int ZB = (NSEG + 255) / 256;            // 1875
    const int FUSED_BLKS = (N_NODES + 63) / 64;   // 938

    k_bt<<<64, 256, 0, stream>>>(rel_W, root_W, Btb);
    k_embed<<<512, 256, 0, stream>>>(x, emb_W, emb_b, (ushort*)h0);
    k_zero<<<(2 * NSEG + 255) / 256, 256, 0, stream>>>(deg, 2 * NSEG);
    k_deg<<<1024, 256, 0, stream>>>(dstv, etype, deg);
    k_scan1<<<ZB, 256, 0, stream>>>(deg, rp, bs, NSEG);
    k_scanmid<<<1, 256, 0, stream>>>(bs, ZB);
    k_scanadd<<<ZB, 256, 0, stream>>>(rp, bs, NSEG, 1);
    k_scatter<<<1024, 256, 0, stream>>>(srcv, dstv, etype, rp, fill, csr16);

    for (int l = 0; l < 2; ++l) {
        const uint* hin = l ? h1 : h0;
        uint* hout = l ? h0 : h1;
        k_fused<<<FUSED_BLKS, 256, 0, stream>>>(
            hin, rp, csr16,
            Btb + (size_t)l * 131072,
            conv_b + l * 128, ln_g + l * 128, ln_b + l * 128,
            hout, N_NODES);
    }
    k_cls<<<469, 256, 0, stream>>>((const ushort*)h0, cls_W1, cls_b1, cls_lg, cls_lb,
                                   cls_W2, cls_b2, (float*)d_out, N_NODES);
}

// Round 6
// 288.230 us; speedup vs baseline: 1.3812x; 1.3812x over previous
//
#include <hip/hip_runtime.h>
#include <hip/hip_bf16.h>

typedef unsigned int uint;
typedef unsigned short ushort;

#define N_NODES 60000
#define N_EDGES 600000
#define NREL 7
#define D_IN 64
#define DHID 128
#define LEPS 1e-5f

typedef __attribute__((ext_vector_type(8))) short bf16x8v;   // 8 bf16 = 4 VGPRs
typedef __attribute__((ext_vector_type(4))) float f32x4v;    // MFMA accumulator

#define AS1C(p) ((const __attribute__((address_space(1))) void*)(p))
#define AS3(p)  ((__attribute__((address_space(3))) void*)(p))

__device__ __forceinline__ float bf2f(uint u16) {
    return __uint_as_float(u16 << 16);
}
__device__ __forceinline__ uint f2bf(float f) {
    uint u = __float_as_uint(f);
    uint lsb = (u >> 16) & 1u;
    u += 0x7fffu + lsb;
    return u >> 16;
}
__device__ __forceinline__ uint pack2(float a, float b) {
    return f2bf(a) | (f2bf(b) << 16);
}

// ---------------- B transpose + f32->bf16: Bt[l][j 0..127][k 0..1023] ----------
__global__ __launch_bounds__(256) void k_bt(const float* __restrict__ relW,
                                            const float* __restrict__ rootW,
                                            ushort* __restrict__ Bt) {
    const int l  = blockIdx.x >> 5;
    const int kt = (blockIdx.x >> 1) & 15;   // 64-k tile
    const int jt = blockIdx.x & 1;           // 64-j tile
    __shared__ float t[64][65];
    const int tid = threadIdx.x;
    #pragma unroll
    for (int i = 0; i < 4; ++i) {
        const int idx = i * 256 + tid;       // 0..1023
        const int kr = idx >> 4;             // 0..63
        const int j4 = idx & 15;             // float4 index
        const int kg = kt * 64 + kr;
        const float* src = (kg < 896)
            ? (relW + (size_t)l * 896 * 128 + (size_t)kg * 128)
            : (rootW + (size_t)l * 128 * 128 + (size_t)(kg - 896) * 128);
        const float4 v = *(const float4*)(src + jt * 64 + j4 * 4);
        t[kr][j4 * 4 + 0] = v.x; t[kr][j4 * 4 + 1] = v.y;
        t[kr][j4 * 4 + 2] = v.z; t[kr][j4 * 4 + 3] = v.w;
    }
    __syncthreads();
    uint* btd = (uint*)Bt;
    #pragma unroll
    for (int i = 0; i < 8; ++i) {
        const int idx = i * 256 + tid;       // 0..2047
        const int jr = idx >> 5;             // 0..63
        const int kd = idx & 31;             // dword within 64-k tile
        const uint w = pack2(t[kd * 2][jr], t[kd * 2 + 1][jr]);
        btd[(size_t)l * 65536 + (size_t)(jt * 64 + jr) * 512 + kt * 32 + kd] = w;
    }
}

// ---------------- emb_W transpose: Bte[j 0..127][k 0..63] bf16 -----------------
__global__ __launch_bounds__(256) void k_bte(const float* __restrict__ embW,
                                             ushort* __restrict__ Bte) {
    const int jt = blockIdx.x;               // 0..1
    __shared__ float t[64][65];
    const int tid = threadIdx.x;
    #pragma unroll
    for (int i = 0; i < 4; ++i) {
        const int idx = i * 256 + tid;       // 0..1023
        const int kr = idx >> 4;             // 0..63
        const int j4 = idx & 15;
        const float4 v = *(const float4*)(embW + (size_t)kr * 128 + jt * 64 + j4 * 4);
        t[kr][j4 * 4 + 0] = v.x; t[kr][j4 * 4 + 1] = v.y;
        t[kr][j4 * 4 + 2] = v.z; t[kr][j4 * 4 + 3] = v.w;
    }
    __syncthreads();
    uint* btd = (uint*)Bte;
    #pragma unroll
    for (int i = 0; i < 8; ++i) {
        const int idx = i * 256 + tid;       // 0..2047
        const int jr = idx >> 5;             // 0..63
        const int kd = idx & 31;             // dword 0..31 (k pair)
        const uint w = pack2(t[kd * 2][jr], t[kd * 2 + 1][jr]);
        btd[(size_t)(jt * 64 + jr) * 32 + kd] = w;
    }
}

// ---------------- MFMA embed: h0 = clip(x,-10,10)@emb_W + emb_b (bf16) ---------
// 64-node blocks, 4 waves (2x2), K=64 (2 kh halves), direct register epilogue.
__global__ __launch_bounds__(256) void k_emb(const float* __restrict__ x,
                                             const ushort* __restrict__ Bte, // [128][64]
                                             const float* __restrict__ bias,
                                             ushort* __restrict__ h, int nrows) {
    __shared__ alignas(16) ushort sa[64 * 64];    // 8 KB, swizzled granules
    __shared__ alignas(16) ushort sb[128 * 64];   // 16 KB
    const int tid = threadIdx.x;
    const int lane = tid & 63;
    const int wid = tid >> 6;
    const int wrow = wid >> 1, wcol = wid & 1;
    const int l15 = lane & 15, lh = lane >> 4;
    const int row0 = blockIdx.x * 64;

    // stage A: 512 granules (64 rows x 8), clip + f32->bf16
    #pragma unroll
    for (int i = 0; i < 2; ++i) {
        const int p = i * 256 + tid;
        const int row = p >> 3, gq = p & 7;
        const int n = min(row0 + row, nrows - 1);
        const float4 xa = *(const float4*)(x + (size_t)n * 64 + gq * 8);
        const float4 xb = *(const float4*)(x + (size_t)n * 64 + gq * 8 + 4);
        uint w[4];
        w[0] = pack2(fminf(fmaxf(xa.x, -10.f), 10.f), fminf(fmaxf(xa.y, -10.f), 10.f));
        w[1] = pack2(fminf(fmaxf(xa.z, -10.f), 10.f), fminf(fmaxf(xa.w, -10.f), 10.f));
        w[2] = pack2(fminf(fmaxf(xb.x, -10.f), 10.f), fminf(fmaxf(xb.y, -10.f), 10.f));
        w[3] = pack2(fminf(fmaxf(xb.z, -10.f), 10.f), fminf(fmaxf(xb.w, -10.f), 10.f));
        *(uint4*)&sa[(row * 8 + (gq ^ (row & 7))) * 8] = make_uint4(w[0], w[1], w[2], w[3]);
    }
    // stage B: 1024 granules (128 rows x 8)
    #pragma unroll
    for (int i = 0; i < 4; ++i) {
        const int p = i * 256 + tid;
        const int row = p >> 3, gq = p & 7;
        const uint4 v = *(const uint4*)((const uint*)Bte + (size_t)row * 32 + gq * 4);
        *(uint4*)&sb[(row * 8 + (gq ^ (row & 7))) * 8] = v;
    }
    float bv[4];
    #pragma unroll
    for (int fn = 0; fn < 4; ++fn) bv[fn] = bias[wcol * 64 + fn * 16 + l15];
    __syncthreads();

    f32x4v acc[2][4];
    #pragma unroll
    for (int fm = 0; fm < 2; ++fm)
        #pragma unroll
        for (int fn = 0; fn < 4; ++fn)
            acc[fm][fn] = (f32x4v){0.f, 0.f, 0.f, 0.f};
    #pragma unroll
    for (int kh = 0; kh < 2; ++kh) {
        bf16x8v af[2], bfr[4];
        #pragma unroll
        for (int fm = 0; fm < 2; ++fm) {
            const int rowa = wrow * 32 + fm * 16 + l15;
            const int slot = (kh * 4 + lh) ^ (rowa & 7);
            af[fm] = *(const bf16x8v*)&sa[rowa * 64 + slot * 8];
        }
        #pragma unroll
        for (int fn = 0; fn < 4; ++fn) {
            const int rowb = wcol * 64 + fn * 16 + l15;
            const int slot = (kh * 4 + lh) ^ (rowb & 7);
            bfr[fn] = *(const bf16x8v*)&sb[rowb * 64 + slot * 8];
        }
        #pragma unroll
        for (int fm = 0; fm < 2; ++fm)
            #pragma unroll
            for (int fn = 0; fn < 4; ++fn)
                acc[fm][fn] = __builtin_amdgcn_mfma_f32_16x16x32_bf16(
                    af[fm], bfr[fn], acc[fm][fn], 0, 0, 0);
    }
    #pragma unroll
    for (int fm = 0; fm < 2; ++fm)
        #pragma unroll
        for (int r = 0; r < 4; ++r) {
            const int row = row0 + wrow * 32 + fm * 16 + lh * 4 + r;
            if (row < nrows) {
                #pragma unroll
                for (int fn = 0; fn < 4; ++fn) {
                    const int col = wcol * 64 + fn * 16 + l15;
                    h[(size_t)row * 128 + col] = (ushort)f2bf(acc[fm][fn][r] + bv[fn]);
                }
            }
        }
}

// ---------------- CSR build: node-keyed list + per-(node,rel) counts ----------
__global__ void k_deg(const int* __restrict__ dst, const int* __restrict__ et,
                      int* __restrict__ degn, int* __restrict__ deg8) {
    for (int e = blockIdx.x * 256 + threadIdx.x; e < N_EDGES; e += gridDim.x * 256) {
        const int d = dst[e];
        atomicAdd(&degn[d], 1);
        atomicAdd(&deg8[d * 8 + et[e]], 1);
    }
}
__global__ void k_scan1(const int* __restrict__ in, int* __restrict__ out,
                        int* __restrict__ bsum, int n) {
    __shared__ int s[256];
    const int t = threadIdx.x;
    const int i = blockIdx.x * 256 + t;
    const int v = (i < n) ? in[i] : 0;
    s[t] = v;
    __syncthreads();
    for (int o = 1; o < 256; o <<= 1) {
        int uu = (t >= o) ? s[t - o] : 0;
        __syncthreads();
        s[t] += uu;
        __syncthreads();
    }
    if (i < n) out[i] = s[t] - v;   // exclusive within block
    if (t == 255) bsum[blockIdx.x] = s[255];
}
__global__ void k_scanmid(int* __restrict__ bs, int nb) {
    __shared__ int s[256];
    __shared__ int carrys;
    const int t = threadIdx.x;
    if (t == 0) carrys = 0;
    __syncthreads();
    const int nch = (nb + 255) / 256;
    for (int ch = 0; ch < nch; ++ch) {
        const int i = ch * 256 + t;
        const int v = (i < nb) ? bs[i] : 0;
        s[t] = v;
        __syncthreads();
        for (int o = 1; o < 256; o <<= 1) {
            int uu = (t >= o) ? s[t - o] : 0;
            __syncthreads();
            s[t] += uu;
            __syncthreads();
        }
        const int carry = carrys;
        if (i < nb) bs[i] = s[t] - v + carry;
        __syncthreads();
        if (t == 255) carrys = carry + s[255];
        __syncthreads();
    }
}
__global__ void k_scanadd(int* __restrict__ a, const int* __restrict__ bsums,
                          int n, int setlast) {
    const int i = blockIdx.x * 256 + threadIdx.x;
    if (i < n) a[i] += bsums[blockIdx.x];
    if (setlast && blockIdx.x == 0 && threadIdx.x == 0) a[n] = N_EDGES;
}
__global__ void k_scatter(const int* __restrict__ src, const int* __restrict__ dst,
                          const int* __restrict__ et, const int* __restrict__ rp,
                          int* __restrict__ fill, uint* __restrict__ csr32) {
    for (int e = blockIdx.x * 256 + threadIdx.x; e < N_EDGES; e += gridDim.x * 256) {
        const int d = dst[e];
        const int p = rp[d] + atomicAdd(&fill[d], 1);
        csr32[p] = (uint)src[e] | ((uint)et[e] << 16);
    }
}

// ---------------- aggregation v2: wave/node, FLAT 4-deep-batched edge loop ----
#define ACCR(R, V) do {                                              \
    const float x0_ = bf2f((V) & 0xFFFFu), x1_ = bf2f((V) >> 16);    \
    switch (R) {                                                     \
        case 0: a0[0] += x0_; a1[0] += x1_; break;                   \
        case 1: a0[1] += x0_; a1[1] += x1_; break;                   \
        case 2: a0[2] += x0_; a1[2] += x1_; break;                   \
        case 3: a0[3] += x0_; a1[3] += x1_; break;                   \
        case 4: a0[4] += x0_; a1[4] += x1_; break;                   \
        case 5: a0[5] += x0_; a1[5] += x1_; break;                   \
        default: a0[6] += x0_; a1[6] += x1_; break;                  \
    } } while (0)

__global__ __launch_bounds__(256) void k_agg(const uint* __restrict__ h32,
                                             const int* __restrict__ rp,
                                             const int* __restrict__ cnt8,
                                             const uint* __restrict__ csr32,
                                             uint* __restrict__ M32) {
    const int wave = (blockIdx.x * 256 + threadIdx.x) >> 6;
    const int lane = threadIdx.x & 63;
    const int nwaves = gridDim.x * 4;
    for (int n = wave; n < N_NODES; n += nwaves) {
        const int beg = rp[n], end = rp[n + 1];
        float a0[NREL], a1[NREL];
        #pragma unroll
        for (int r = 0; r < NREL; ++r) { a0[r] = 0.f; a1[r] = 0.f; }
        int e = beg;
        #pragma unroll 1
        for (; e + 4 <= end; e += 4) {
            const int t0 = __builtin_amdgcn_readfirstlane((int)csr32[e]);
            const int t1 = __builtin_amdgcn_readfirstlane((int)csr32[e + 1]);
            const int t2 = __builtin_amdgcn_readfirstlane((int)csr32[e + 2]);
            const int t3 = __builtin_amdgcn_readfirstlane((int)csr32[e + 3]);
            const uint v0 = h32[(size_t)(t0 & 0xFFFF) * 64 + lane];
            const uint v1 = h32[(size_t)(t1 & 0xFFFF) * 64 + lane];
            const uint v2 = h32[(size_t)(t2 & 0xFFFF) * 64 + lane];
            const uint v3 = h32[(size_t)(t3 & 0xFFFF) * 64 + lane];
            ACCR(t0 >> 16, v0);
            ACCR(t1 >> 16, v1);
            ACCR(t2 >> 16, v2);
            ACCR(t3 >> 16, v3);
        }
        #pragma unroll 1
        for (; e < end; ++e) {
            const int t0 = __builtin_amdgcn_readfirstlane((int)csr32[e]);
            const uint v0 = h32[(size_t)(t0 & 0xFFFF) * 64 + lane];
            ACCR(t0 >> 16, v0);
        }
        const int4 ca = *(const int4*)(cnt8 + n * 8);
        const int4 cb = *(const int4*)(cnt8 + n * 8 + 4);
        const int cnt[NREL] = {ca.x, ca.y, ca.z, ca.w, cb.x, cb.y, cb.z};
        const size_t base = (size_t)n * 448 + lane;
        #pragma unroll
        for (int r = 0; r < NREL; ++r) {
            const float sc = 1.f / (float)max(cnt[r], 1);
            M32[base + r * 64] = pack2(a0[r] * sc, a1[r] * sc);
        }
    }
}

// ---------------- MFMA GEMM + LayerNorm + ReLU (8 waves, gload_lds pipeline) ----
__global__ __launch_bounds__(512) void k_gemm_mfma(const ushort* __restrict__ A1,  // [N][896]
                                                   const ushort* __restrict__ A2,  // [N][128]
                                                   const ushort* __restrict__ Bt,  // [128][1024]
                                                   const float* __restrict__ bias,
                                                   const float* __restrict__ g,
                                                   const float* __restrict__ bb,
                                                   uint* __restrict__ out,         // bf16 dwords
                                                   int nrows) {
    __shared__ alignas(16) union {
        struct { ushort a[2][8192]; ushort b[2][8192]; } s;   // 64 KB staging (dbuf)
        float ep[64 * 132];                                   // 33 KB epilogue half
    } u;
    __shared__ float sbi[DHID], sg[DHID], sbb[DHID];

    const int tid = threadIdx.x;
    if (tid < DHID) { sbi[tid] = bias[tid]; sg[tid] = g[tid]; sbb[tid] = bb[tid]; }
    const int lane = tid & 63;
    const int wid = tid >> 6;        // 0..7
    const int wrow = wid >> 1;       // 0..3: 32-row band
    const int wcol = wid & 1;        // 0..1: 64-col band
    const int row0 = blockIdx.x * 128;

    int prow[2], pG[2], arow[2];
    #pragma unroll
    for (int hf = 0; hf < 2; ++hf) {
        const int p = hf * 512 + wid * 64 + lane;
        const int r = p >> 3;
        prow[hf] = r;
        pG[hf] = (p & 7) ^ (r & 7);
        arow[hf] = min(row0 + r, nrows - 1);
    }

    auto stage = [&](int buf, int kt) {
        #pragma unroll
        for (int hf = 0; hf < 2; ++hf) {
            const ushort* ga = (kt < 14)
                ? (A1 + (size_t)arow[hf] * 896 + kt * 64 + pG[hf] * 8)
                : (A2 + (size_t)arow[hf] * 128 + (kt - 14) * 64 + pG[hf] * 8);
            __builtin_amdgcn_global_load_lds(AS1C(ga),
                AS3(&u.s.a[buf][(hf * 512 + wid * 64) * 8]), 16, 0, 0);
            const ushort* gb = Bt + (size_t)prow[hf] * 1024 + kt * 64 + pG[hf] * 8;
            __builtin_amdgcn_global_load_lds(AS1C(gb),
                AS3(&u.s.b[buf][(hf * 512 + wid * 64) * 8]), 16, 0, 0);
        }
    };

    f32x4v acc[2][4];
    #pragma unroll
    for (int fm = 0; fm < 2; ++fm)
        #pragma unroll
        for (int fn = 0; fn < 4; ++fn)
            acc[fm][fn] = (f32x4v){0.f, 0.f, 0.f, 0.f};

    auto compute = [&](int buf) {
        #pragma unroll
        for (int kh = 0; kh < 2; ++kh) {
            bf16x8v af[2], bfr[4];
            #pragma unroll
            for (int fm = 0; fm < 2; ++fm) {
                const int rowa = wrow * 32 + fm * 16 + (lane & 15);
                const int sa = (kh * 4 + (lane >> 4)) ^ (rowa & 7);
                af[fm] = *(const bf16x8v*)&u.s.a[buf][rowa * 64 + sa * 8];
            }
            #pragma unroll
            for (int fn = 0; fn < 4; ++fn) {
                const int rowb = wcol * 64 + fn * 16 + (lane & 15);
                const int sb = (kh * 4 + (lane >> 4)) ^ (rowb & 7);
                bfr[fn] = *(const bf16x8v*)&u.s.b[buf][rowb * 64 + sb * 8];
            }
            #pragma unroll
            for (int fm = 0; fm < 2; ++fm)
                #pragma unroll
                for (int fn = 0; fn < 4; ++fn)
                    acc[fm][fn] = __builtin_amdgcn_mfma_f32_16x16x32_bf16(
                        af[fm], bfr[fn], acc[fm][fn], 0, 0, 0);
        }
    };

    stage(0, 0);
    #pragma unroll 1
    for (int kt = 0; kt < 16; ++kt) {
        const int cur = kt & 1;
        if (kt < 15) {
            stage(cur ^ 1, kt + 1);
            asm volatile("s_waitcnt vmcnt(4)\n\ts_barrier" ::: "memory");
        } else {
            asm volatile("s_waitcnt vmcnt(0)\n\ts_barrier" ::: "memory");
        }
        compute(cur);
        asm volatile("s_barrier" ::: "memory");
    }
    __syncthreads();

    // -------- fused LayerNorm + ReLU epilogue, two 64-row halves --------
    const int hw = wrow >> 1;
    #pragma unroll 1
    for (int hh = 0; hh < 2; ++hh) {
        if (hw == hh) {
            #pragma unroll
            for (int fm = 0; fm < 2; ++fm) {
                const int rl = (wrow & 1) * 32 + fm * 16 + (lane >> 4) * 4;
                #pragma unroll
                for (int fn = 0; fn < 4; ++fn) {
                    const int cl = wcol * 64 + fn * 16 + (lane & 15);
                    const float bi = sbi[cl];
                    #pragma unroll
                    for (int r = 0; r < 4; ++r)
                        u.ep[(rl + r) * 132 + cl] = acc[fm][fn][r] + bi;
                }
            }
        }
        __syncthreads();
        {
            const int r_loc = tid >> 3, cb = tid & 7;   // 8 threads per row
            const int row_g = row0 + hh * 64 + r_loc;
            float v[16];
            float s = 0.f, sq = 0.f;
            #pragma unroll
            for (int q = 0; q < 4; ++q) {
                const float4 t4 = *(const float4*)&u.ep[r_loc * 132 + cb * 16 + q * 4];
                v[4 * q + 0] = t4.x; v[4 * q + 1] = t4.y;
                v[4 * q + 2] = t4.z; v[4 * q + 3] = t4.w;
                s += t4.x + t4.y + t4.z + t4.w;
                sq += t4.x * t4.x + t4.y * t4.y + t4.z * t4.z + t4.w * t4.w;
            }
            s += __shfl_xor(s, 1, 64); sq += __shfl_xor(sq, 1, 64);
            s += __shfl_xor(s, 2, 64); sq += __shfl_xor(sq, 2, 64);
            s += __shfl_xor(s, 4, 64); sq += __shfl_xor(sq, 4, 64);
            const float mean = s * (1.f / 128.f);
            const float var = sq * (1.f / 128.f) - mean * mean;
            const float rs = rsqrtf(var + LEPS);
            if (row_g < nrows) {
                uint o[8];
                #pragma unroll
                for (int q2 = 0; q2 < 8; ++q2) {
                    const int c0 = cb * 16 + 2 * q2;
                    const float va = fmaxf((v[2 * q2]     - mean) * rs * sg[c0]     + sbb[c0],     0.f);
                    const float vb = fmaxf((v[2 * q2 + 1] - mean) * rs * sg[c0 + 1] + sbb[c0 + 1], 0.f);
                    o[q2] = pack2(va, vb);
                }
                uint* op = out + (size_t)row_g * 64 + cb * 8;
                *(uint4*)(op + 0) = make_uint4(o[0], o[1], o[2], o[3]);
                *(uint4*)(op + 4) = make_uint4(o[4], o[5], o[6], o[7]);
            }
        }
        __syncthreads();
    }
}

// ---------------- classifier: MFMA h@W1 + in-register LN/ReLU/W2-dot ----------
__global__ __launch_bounds__(256) void k_cls(const ushort* __restrict__ h16,
                                             const float* __restrict__ W1,   // [128][64]
                                             const float* __restrict__ b1,
                                             const float* __restrict__ lg,
                                             const float* __restrict__ lb,
                                             const float* __restrict__ W2,   // [64]
                                             const float* __restrict__ b2,
                                             float* __restrict__ outp, int nrows) {
    __shared__ ushort Bs[16 * 64 * 8];   // [k-granule g][col j'][8 bf16], 16 KB
    const int tid = threadIdx.x;
    #pragma unroll
    for (int i = 0; i < 8; ++i) {
        const int q = i * 256 + tid;     // 2048 float4 = 8192 f32
        const int k = q >> 4;            // 0..127
        const int j0 = (q & 15) * 4;
        const float4 w = *(const float4*)(W1 + (size_t)k * 64 + j0);
        const int gg = k >> 3, kp = k & 7;
        const int jx = (gg & 3) << 4;
        Bs[(gg * 64 + ((j0 + 0) ^ jx)) * 8 + kp] = (ushort)f2bf(w.x);
        Bs[(gg * 64 + ((j0 + 1) ^ jx)) * 8 + kp] = (ushort)f2bf(w.y);
        Bs[(gg * 64 + ((j0 + 2) ^ jx)) * 8 + kp] = (ushort)f2bf(w.z);
        Bs[(gg * 64 + ((j0 + 3) ^ jx)) * 8 + kp] = (ushort)f2bf(w.w);
    }
    const int lane = tid & 63, wid = tid >> 6;
    const int l15 = lane & 15, lh = lane >> 4;
    float lgv[4], lbv[4], w2v[4], b1v[4];
    #pragma unroll
    for (int fn = 0; fn < 4; ++fn) {
        const int col = fn * 16 + l15;
        lgv[fn] = lg[col]; lbv[fn] = lb[col]; w2v[fn] = W2[col]; b1v[fn] = b1[col];
    }
    const float b2v = b2[0];
    __syncthreads();

    const int row0 = blockIdx.x * 128;
    f32x4v acc[2][4];
    #pragma unroll
    for (int fm = 0; fm < 2; ++fm)
        #pragma unroll
        for (int fn = 0; fn < 4; ++fn)
            acc[fm][fn] = (f32x4v){0.f, 0.f, 0.f, 0.f};

    #pragma unroll
    for (int kk = 0; kk < 4; ++kk) {
        bf16x8v af[2], bfr[4];
        #pragma unroll
        for (int fm = 0; fm < 2; ++fm) {
            const int row = min(row0 + wid * 32 + fm * 16 + l15, nrows - 1);
            af[fm] = *(const bf16x8v*)(h16 + (size_t)row * 128 + kk * 32 + lh * 8);
        }
        #pragma unroll
        for (int fn = 0; fn < 4; ++fn) {
            const int gg = kk * 4 + lh;
            const int jc = fn * 16 + l15;
            bfr[fn] = *(const bf16x8v*)&Bs[(gg * 64 + (jc ^ ((gg & 3) << 4))) * 8];
        }
        #pragma unroll
        for (int fm = 0; fm < 2; ++fm)
            #pragma unroll
            for (int fn = 0; fn < 4; ++fn)
                acc[fm][fn] = __builtin_amdgcn_mfma_f32_16x16x32_bf16(
                    af[fm], bfr[fn], acc[fm][fn], 0, 0, 0);
    }

    #pragma unroll
    for (int fm = 0; fm < 2; ++fm)
        #pragma unroll
        for (int r = 0; r < 4; ++r) {
            float cv[4];
            float s = 0.f, sq = 0.f;
            #pragma unroll
            for (int fn = 0; fn < 4; ++fn) {
                cv[fn] = acc[fm][fn][r] + b1v[fn];
                s += cv[fn]; sq += cv[fn] * cv[fn];
            }
            s += __shfl_xor(s, 1, 64); sq += __shfl_xor(sq, 1, 64);
            s += __shfl_xor(s, 2, 64); sq += __shfl_xor(sq, 2, 64);
            s += __shfl_xor(s, 4, 64); sq += __shfl_xor(sq, 4, 64);
            s += __shfl_xor(s, 8, 64); sq += __shfl_xor(sq, 8, 64);
            const float mean = s * (1.f / 64.f);
            const float var = sq * (1.f / 64.f) - mean * mean;
            const float rs = rsqrtf(var + LEPS);
            float dot = 0.f;
            #pragma unroll
            for (int fn = 0; fn < 4; ++fn)
                dot += fmaxf((cv[fn] - mean) * rs * lgv[fn] + lbv[fn], 0.f) * w2v[fn];
            dot += __shfl_xor(dot, 1, 64);
            dot += __shfl_xor(dot, 2, 64);
            dot += __shfl_xor(dot, 4, 64);
            dot += __shfl_xor(dot, 8, 64);
            const int row = row0 + wid * 32 + fm * 16 + lh * 4 + r;
            if (l15 == 0 && row < nrows) outp[row] = dot + b2v;
        }
}

extern "C" void kernel_launch(void* const* d_in, const int* in_sizes, int n_in,
                              void* d_out, int out_size, void* d_ws, size_t ws_size,
                              hipStream_t stream) {
    const float* x      = (const float*)d_in[0];
    const int*   eidx   = (const int*)d_in[1];
    const int*   etype  = (const int*)d_in[2];
    const float* emb_W  = (const float*)d_in[3];
    const float* emb_b  = (const float*)d_in[4];
    const float* rel_W  = (const float*)d_in[5];
    const float* root_W = (const float*)d_in[6];
    const float* conv_b = (const float*)d_in[7];
    const float* ln_g   = (const float*)d_in[8];
    const float* ln_b   = (const float*)d_in[9];
    const float* cls_W1 = (const float*)d_in[10];
    const float* cls_b1 = (const float*)d_in[11];
    const float* cls_lg = (const float*)d_in[12];
    const float* cls_lb = (const float*)d_in[13];
    const float* cls_W2 = (const float*)d_in[14];
    const float* cls_b2 = (const float*)d_in[15];

    const int* srcv = eidx;
    const int* dstv = eidx + N_EDGES;

    // workspace layout (~141 MB)
    char* ws = (char*)d_ws;
    size_t off = 0;
    auto alloc = [&](size_t bytes) { void* p = ws + off; off += (bytes + 255) & ~(size_t)255; return p; };
    uint*   h0    = (uint*)alloc((size_t)N_NODES * 64 * 4);     // bf16 h, dword-packed
    uint*   h1    = (uint*)alloc((size_t)N_NODES * 64 * 4);
    uint*   M     = (uint*)alloc((size_t)N_NODES * 448 * 4);    // bf16 means, dword-packed
    int*    rp    = (int*)alloc((size_t)(N_NODES + 1) * 4);
    int*    cnts  = (int*)alloc((size_t)(N_NODES * 10) * 4);    // degn | fill | deg8
    uint*   csr32 = (uint*)alloc((size_t)N_EDGES * 4);
    ushort* Btb   = (ushort*)alloc((size_t)2 * 128 * 1024 * 2); // bf16 B^T per layer
    ushort* Bte   = (ushort*)alloc((size_t)128 * 64 * 2);       // bf16 emb_W^T
    int*    bs    = (int*)alloc(4096);
    int*    degn  = cnts;
    int*    fill  = cnts + N_NODES;
    int*    deg8  = cnts + 2 * N_NODES;
    (void)ws_size; (void)n_in; (void)in_sizes; (void)out_size;

    const int SB = (N_NODES + 255) / 256;         // 235
    const int GEMM_BLKS = (N_NODES + 127) / 128;  // 469
    const int EMB_BLKS = (N_NODES + 63) / 64;     // 938

    k_bt<<<64, 256, 0, stream>>>(rel_W, root_W, Btb);
    k_bte<<<2, 256, 0, stream>>>(emb_W, Bte);
    k_emb<<<EMB_BLKS, 256, 0, stream>>>(x, Bte, emb_b, (ushort*)h0, N_NODES);
    hipMemsetAsync(cnts, 0, (size_t)(N_NODES * 10) * 4, stream);
    k_deg<<<1024, 256, 0, stream>>>(dstv, etype, degn, deg8);
    k_scan1<<<SB, 256, 0, stream>>>(degn, rp, bs, N_NODES);
    k_scanmid<<<1, 256, 0, stream>>>(bs, SB);
    k_scanadd<<<SB, 256, 0, stream>>>(rp, bs, N_NODES, 1);
    k_scatter<<<1024, 256, 0, stream>>>(srcv, dstv, etype, rp, fill, csr32);

    for (int l = 0; l < 2; ++l) {
        const uint* hin = l ? h1 : h0;
        uint* hout = l ? h0 : h1;
        k_agg<<<2048, 256, 0, stream>>>(hin, rp, deg8, csr32, M);
        k_gemm_mfma<<<GEMM_BLKS, 512, 0, stream>>>(
            (const ushort*)M, (const ushort*)hin,
            Btb + (size_t)l * 131072,
            conv_b + l * 128, ln_g + l * 128, ln_b + l * 128,
            hout, N_NODES);
    }
    k_cls<<<469, 256, 0, stream>>>((const ushort*)h0, cls_W1, cls_b1, cls_lg, cls_lb,
                                   cls_W2, cls_b2, (float*)d_out, N_NODES);
}